// Round 1
// baseline (428.813 us; speedup 1.0000x reference)
//
#include <hip/hip_runtime.h>
#include <math.h>

#define XS 2048
#define NN 4096
#define ZS 64
#define DD 6208
#define D4 1552              // DD/4
#define Z0 (XS + NN)         // 6144
#define TOPK 16
#define ZTOPK 8
#define EPS_TIE 1e-9f
#define RNDC 0.5f
#define NXUPD 2047           // x rows updated: 0..2046

// d_out offsets (floats): [z_response(64) | final(6208) | neurons(DD*DD) | ages(6208)]
#define OUT_FINAL 64
#define OUT_NEUR  (64 + DD)                       // 6272
#define OUT_AGES  (OUT_NEUR + (size_t)DD * DD)    // 38545536

// ws offsets (floats)
#define WS_RESP   0
#define WS_INPT   DD
#define WS_MIXX   (2 * DD)
#define WS_MIXZ   (3 * DD)
#define WS_MIXY   (4 * DD)
#define WS_SCAL   (5 * DD)           // 32 floats: 0 Sii,1 SmmX,2 SmiX,3 SmmZ,4 SmiZ,5 SmmY,6 SmiY,7 denomX
#define WS_SELROW (WS_SCAL + 32)     // 24 ints (8 z rows then 16 y rows)
#define WS_SELC   (WS_SELROW + 24)   // 24 floats: v/a
#define WS_SELW   (WS_SELC + 24)     // 24 floats: (a-1)/a
#define WS_TOTAL  (WS_SELW + 32)

// ---------------- Phase 1: matvec + copy rows>=2047 + mix_x + stage inpt ----
__global__ __launch_bounds__(256) void k_phase1(
    const float* __restrict__ x, const float* __restrict__ yr,
    const float* __restrict__ zv, const float* __restrict__ neurons,
    const float* __restrict__ ages, float* __restrict__ ws,
    float* __restrict__ outn)
{
  const int t = threadIdx.x;
  const int b = blockIdx.x;
  const int row0 = b * 8;

  // per-thread inpt chunks (column set fixed: i = t + 256k). 16B chunks never
  // straddle the x/y/z boundaries (2048 and 6144 are multiples of 4).
  float4 inp[7];
  #pragma unroll
  for (int k = 0; k < 7; ++k) {
    int i = t + 256 * k;
    if (i < D4) {
      int col = i * 4;
      float4 v;
      if (col < XS)      v = *(const float4*)(x + col);
      else if (col < Z0) v = *(const float4*)(yr + (col - XS));
      else               v = *(const float4*)(zv + (col - Z0));
      inp[k] = v;
    } else {
      inp[k] = make_float4(0.f, 0.f, 0.f, 0.f);
    }
  }
  if (b == 0) {  // stage inpt for later phases
    #pragma unroll
    for (int k = 0; k < 7; ++k) {
      int i = t + 256 * k;
      if (i < D4) ((float4*)(ws + WS_INPT))[i] = inp[k];
    }
  }

  const bool hasx = (row0 < NXUPD);
  float wr[8];
  #pragma unroll
  for (int r = 0; r < 8; ++r) {
    int row = row0 + r;
    float a = ages[row];
    wr[r] = (row < NXUPD) ? (a - 1.f) / a : 0.f;
  }

  float dot[8] = {0.f,0.f,0.f,0.f,0.f,0.f,0.f,0.f};
  float4 mix[7];
  #pragma unroll
  for (int k = 0; k < 7; ++k) mix[k] = make_float4(0.f, 0.f, 0.f, 0.f);

  for (int k = 0; k < 7; ++k) {
    int i = t + 256 * k;
    if (i >= D4) break;  // i strictly increases with k
    float4 w4 = inp[k];
    #pragma unroll
    for (int r = 0; r < 8; ++r) {
      int row = row0 + r;
      const float4 a4 = *(const float4*)(neurons + (size_t)row * DD + (size_t)i * 4);
      dot[r] = fmaf(a4.x, w4.x, fmaf(a4.y, w4.y, fmaf(a4.z, w4.z, fmaf(a4.w, w4.w, dot[r]))));
      if (hasx) {
        mix[k].x = fmaf(wr[r], a4.x, mix[k].x);
        mix[k].y = fmaf(wr[r], a4.y, mix[k].y);
        mix[k].z = fmaf(wr[r], a4.z, mix[k].z);
        mix[k].w = fmaf(wr[r], a4.w, mix[k].w);
      }
      if (row >= NXUPD)  // rows < 2047 get fully rewritten in phase 4 — skip copy
        *(float4*)(outn + (size_t)row * DD + (size_t)i * 4) = a4;
    }
  }

  // block-reduce the 8 dots
  __shared__ float wred[4][8];
  const int lane = t & 63, wv = t >> 6;
  #pragma unroll
  for (int r = 0; r < 8; ++r) {
    float v = dot[r];
    #pragma unroll
    for (int m = 32; m >= 1; m >>= 1) v += __shfl_xor(v, m);
    if (lane == 0) wred[wv][r] = v;
  }
  __syncthreads();
  if (t < 8) ws[WS_RESP + row0 + t] = wred[0][t] + wred[1][t] + wred[2][t] + wred[3][t];

  if (hasx) {
    #pragma unroll
    for (int k = 0; k < 7; ++k) {
      int i = t + 256 * k;
      if (i < D4) {
        atomicAdd(ws + WS_MIXX + i * 4 + 0, mix[k].x);
        atomicAdd(ws + WS_MIXX + i * 4 + 1, mix[k].y);
        atomicAdd(ws + WS_MIXX + i * 4 + 2, mix[k].z);
        atomicAdd(ws + WS_MIXX + i * 4 + 3, mix[k].w);
      }
    }
  }
}

// ---------------- Phase 2: top-ks, final, z_response, ages, scalars --------
__global__ __launch_bounds__(1024) void k_phase2(
    const float* __restrict__ ages, float* __restrict__ ws, float* __restrict__ out)
{
  const int t = threadIdx.x;
  __shared__ float sv[NN];            // y working copy (16 KB)
  __shared__ float swv[64];
  __shared__ int   swi[16];
  __shared__ float s_zval[ZTOPK + 1];
  __shared__ int   s_zidx[ZTOPK + 1];
  __shared__ float s_yval[TOPK + 1];
  __shared__ int   s_yidx[TOPK + 1];
  __shared__ float s_denx, s_ty;
  __shared__ float s_z64[ZS];

  float* resp = ws + WS_RESP;

  // ---- z top-9 (wave 0, lex-max (v,-i) butterfly => jax tie-break) ----
  if (t < ZS) s_z64[t] = resp[Z0 + t];
  __syncthreads();
  if (t < 64) {
    float v = s_z64[t];
    for (int j = 0; j <= ZTOPK; ++j) {
      float bv = v; int bi = t;
      #pragma unroll
      for (int m = 1; m < 64; m <<= 1) {
        float ov = __shfl_xor(bv, m);
        int   oi = __shfl_xor(bi, m);
        if (ov > bv || (ov == bv && oi < bi)) { bv = ov; bi = oi; }
      }
      if (t == 0) { s_zval[j] = bv; s_zidx[j] = bi; }
      if (t == bi) v = -INFINITY;
    }
  }

  // ---- x max & all-zero flag ----
  float lm = -INFINITY; int nz = 0;
  for (int i = t; i < XS; i += 1024) { float v = resp[i]; lm = fmaxf(lm, v); nz |= (v != 0.f); }
  #pragma unroll
  for (int m = 1; m < 64; m <<= 1) { lm = fmaxf(lm, __shfl_xor(lm, m)); nz |= __shfl_xor(nz, m); }
  if ((t & 63) == 0) { swv[t >> 6] = lm; swi[t >> 6] = nz; }
  __syncthreads();
  if (t == 0) {
    float m2 = -INFINITY; int n2 = 0;
    for (int q = 0; q < 16; ++q) { m2 = fmaxf(m2, swv[q]); n2 |= swi[q]; }
    float tx = n2 ? 0.f : 1.f;
    s_denx = m2 + EPS_TIE * tx * RNDC;
  }
  __syncthreads();

  // ---- y top-17 ----
  for (int i = t; i < NN; i += 1024) sv[i] = resp[XS + i];
  __syncthreads();
  for (int j = 0; j <= TOPK; ++j) {
    float bv = -INFINITY; int bi = 0x7fffffff;
    for (int i = t; i < NN; i += 1024) { float v = sv[i]; if (v > bv || (v == bv && i < bi)) { bv = v; bi = i; } }
    #pragma unroll
    for (int m = 1; m < 64; m <<= 1) {
      float ov = __shfl_xor(bv, m); int oi = __shfl_xor(bi, m);
      if (ov > bv || (ov == bv && oi < bi)) { bv = ov; bi = oi; }
    }
    if ((t & 63) == 0) { swv[t >> 6] = bv; swi[t >> 6] = bi; }
    __syncthreads();
    if (t == 0) {
      float b2 = -INFINITY; int i2 = 0x7fffffff;
      for (int q = 0; q < 16; ++q)
        if (swv[q] > b2 || (swv[q] == b2 && swi[q] < i2)) { b2 = swv[q]; i2 = swi[q]; }
      s_yval[j] = b2; s_yidx[j] = i2; sv[i2] = -INFINITY;
    }
    __syncthreads();
  }
  if (t == 0) {
    float ty = 0.f;
    for (int q = 0; q < TOPK; ++q) if (s_yval[q] == s_yval[TOPK]) ty = 1.f;
    s_ty = ty;
  }
  __syncthreads();

  // ---- final + z_response ----
  const float denx  = s_denx;
  const float zlast = s_zval[ZTOPK];
  const float zden  = s_zval[0] - zlast;
  const float ylast = s_yval[TOPK];
  const float yden  = s_yval[0] - ylast + EPS_TIE * s_ty * RNDC;
  float* fin = out + OUT_FINAL;
  for (int i = t; i < DD; i += 1024) {
    float v = 0.f;
    if (i < XS) v = resp[i] / denx;
    fin[i] = v;
  }
  __syncthreads();
  if (t < ZTOPK)                  fin[Z0 + s_zidx[t]] = (s_zval[t] - zlast) / zden;
  else if (t >= 32 && t < 32 + TOPK) { int k = t - 32; fin[XS + s_yidx[k]] = (s_yval[k] - ylast) / yden; }
  if (t >= 128 && t < 192) {      // z_response = final[z0:]
    int i = t - 128;
    float v = 0.f;
    for (int k = 0; k < ZTOPK; ++k) if (s_zidx[k] == i) v = (s_zval[k] - zlast) / zden;
    out[i] = v;
  }

  // ---- ages ----
  float* oag = out + OUT_AGES;
  for (int i = t; i < DD; i += 1024) oag[i] = ages[i] + ((i < NXUPD) ? 1.f : 0.f);
  __syncthreads();
  if (t < ZTOPK + TOPK) {
    int row = (t < ZTOPK) ? (Z0 + s_zidx[t]) : (XS + s_yidx[t - ZTOPK]);
    oag[row] = ages[row] + 1.f;
  }

  // ---- scalars: ||inpt||^2, ||mix_x||^2, mix_x . inpt ----
  float sii = 0.f, smm = 0.f, smi = 0.f;
  float* inpt = ws + WS_INPT;
  float* mixx = ws + WS_MIXX;
  for (int i = t; i < DD; i += 1024) {
    float ip = inpt[i], mx = mixx[i];
    sii = fmaf(ip, ip, sii); smm = fmaf(mx, mx, smm); smi = fmaf(mx, ip, smi);
  }
  #pragma unroll
  for (int m = 1; m < 64; m <<= 1) {
    sii += __shfl_xor(sii, m); smm += __shfl_xor(smm, m); smi += __shfl_xor(smi, m);
  }
  __syncthreads();
  if ((t & 63) == 0) { int w = t >> 6; swv[w] = sii; swv[16 + w] = smm; swv[32 + w] = smi; }
  __syncthreads();
  if (t == 0) {
    float a = 0.f, b = 0.f, c = 0.f;
    for (int q = 0; q < 16; ++q) { a += swv[q]; b += swv[16 + q]; c += swv[32 + q]; }
    float* scal = ws + WS_SCAL;
    scal[0] = a; scal[1] = b; scal[2] = c; scal[7] = denx;
  }

  // ---- selected-row tables for z/y updates ----
  if (t < ZTOPK) {
    int row = Z0 + s_zidx[t];
    ((int*)(ws + WS_SELROW))[t] = row;
    float a = ages[row];
    ws[WS_SELC + t] = s_zval[t] / a;
    ws[WS_SELW + t] = (a - 1.f) / a;
  } else if (t >= 32 && t < 32 + TOPK) {
    int k = t - 32;
    int row = XS + s_yidx[k];
    ((int*)(ws + WS_SELROW))[ZTOPK + k] = row;
    float a = ages[row];
    ws[WS_SELC + ZTOPK + k] = s_yval[k] / a;
    ws[WS_SELW + ZTOPK + k] = (a - 1.f) / a;
  }
}

// ---------------- Phase 3a: mix_z / mix_y accumulation ---------------------
__global__ __launch_bounds__(256) void k_phase3a(
    const float* __restrict__ neurons, float* __restrict__ ws)
{
  const int b = blockIdx.x;
  const int row = ((const int*)(ws + WS_SELROW))[b];
  const float w = ws[WS_SELW + b];
  float* dst = ws + ((b < ZTOPK) ? WS_MIXZ : WS_MIXY);
  const float* src = neurons + (size_t)row * DD;
  for (int i = threadIdx.x; i < DD; i += 256) atomicAdd(dst + i, w * src[i]);
}

// ---------------- Phase 3b: mix_z / mix_y dot scalars ----------------------
__global__ __launch_bounds__(1024) void k_phase3b(float* __restrict__ ws)
{
  const int t = threadIdx.x;
  __shared__ float red[64];
  float* inpt = ws + WS_INPT;
  float smmz = 0.f, smiz = 0.f, smmy = 0.f, smiy = 0.f;
  for (int i = t; i < DD; i += 1024) {
    float ip = inpt[i];
    float mz = ws[WS_MIXZ + i], my = ws[WS_MIXY + i];
    smmz = fmaf(mz, mz, smmz); smiz = fmaf(mz, ip, smiz);
    smmy = fmaf(my, my, smmy); smiy = fmaf(my, ip, smiy);
  }
  #pragma unroll
  for (int m = 1; m < 64; m <<= 1) {
    smmz += __shfl_xor(smmz, m); smiz += __shfl_xor(smiz, m);
    smmy += __shfl_xor(smmy, m); smiy += __shfl_xor(smiy, m);
  }
  __syncthreads();
  if ((t & 63) == 0) { int w = t >> 6; red[w] = smmz; red[16 + w] = smiz; red[32 + w] = smmy; red[48 + w] = smiy; }
  __syncthreads();
  if (t == 0) {
    float a = 0.f, b = 0.f, c = 0.f, d = 0.f;
    for (int q = 0; q < 16; ++q) { a += red[q]; b += red[16 + q]; c += red[32 + q]; d += red[48 + q]; }
    ws[WS_SCAL + 3] = a; ws[WS_SCAL + 4] = b; ws[WS_SCAL + 5] = c; ws[WS_SCAL + 6] = d;
  }
}

// ---------------- Phase 4: write the 2071 updated rows ---------------------
__global__ __launch_bounds__(256) void k_phase4(
    const float* __restrict__ ages, const float* __restrict__ ws,
    float* __restrict__ outn)
{
  const int b = blockIdx.x;
  const int t = threadIdx.x;
  const float sii = ws[WS_SCAL + 0];
  int row; float c, smm, smi; const float* mix;
  if (b < NXUPD) {
    row = b;
    float a = ages[row];
    c = (ws[WS_RESP + row] / ws[WS_SCAL + 7]) / a;   // xvals[row] / age
    mix = ws + WS_MIXX; smm = ws[WS_SCAL + 1]; smi = ws[WS_SCAL + 2];
  } else {
    int k = b - NXUPD;
    row = ((const int*)(ws + WS_SELROW))[k];
    c = ws[WS_SELC + k];
    if (k < ZTOPK) { mix = ws + WS_MIXZ; smm = ws[WS_SCAL + 3]; smi = ws[WS_SCAL + 4]; }
    else           { mix = ws + WS_MIXY; smm = ws[WS_SCAL + 5]; smi = ws[WS_SCAL + 6]; }
  }
  // ||mix + c*inpt||^2 = smm + 2c*smi + c^2*sii
  const float inv = 1.f / (sqrtf(fmaf(c, fmaf(c, sii, 2.f * smi), smm)) + 1e-12f);
  const float* inpt = ws + WS_INPT;
  float* dst = outn + (size_t)row * DD;
  for (int i = t; i < D4; i += 256) {
    float4 m4 = ((const float4*)(mix))[i];
    float4 i4 = ((const float4*)(inpt))[i];
    float4 o;
    o.x = (m4.x + c * i4.x) * inv;
    o.y = (m4.y + c * i4.y) * inv;
    o.z = (m4.z + c * i4.z) * inv;
    o.w = (m4.w + c * i4.w) * inv;
    ((float4*)dst)[i] = o;
  }
}

// ---------------- launcher -------------------------------------------------
extern "C" void kernel_launch(void* const* d_in, const int* in_sizes, int n_in,
                              void* d_out, int out_size, void* d_ws, size_t ws_size,
                              hipStream_t stream)
{
  (void)in_sizes; (void)n_in; (void)out_size; (void)ws_size;
  const float* x    = (const float*)d_in[0];
  const float* zin  = (const float*)d_in[1];   // note setup order: x, z, y_response, neurons, ages
  const float* yr   = (const float*)d_in[2];
  const float* neur = (const float*)d_in[3];
  const float* ages = (const float*)d_in[4];
  float* out = (float*)d_out;
  float* ws  = (float*)d_ws;

  hipMemsetAsync(d_ws, 0, (size_t)WS_TOTAL * sizeof(float), stream);
  k_phase1<<<DD / 8, 256, 0, stream>>>(x, yr, zin, neur, ages, ws, out + OUT_NEUR);
  k_phase2<<<1, 1024, 0, stream>>>(ages, ws, out);
  k_phase3a<<<ZTOPK + TOPK, 256, 0, stream>>>(neur, ws);
  k_phase3b<<<1, 1024, 0, stream>>>(ws);
  k_phase4<<<NXUPD + ZTOPK + TOPK, 256, 0, stream>>>(ages, ws, out + OUT_NEUR);
}

// Round 2
// 360.674 us; speedup vs baseline: 1.1889x; 1.1889x over previous
//
#include <hip/hip_runtime.h>
#include <math.h>

typedef float v4f __attribute__((ext_vector_type(4)));

#define XS 2048
#define NN 4096
#define ZS 64
#define DD 6208
#define D4 1552              // DD/4 chunks per row
#define Z0 (XS + NN)         // 6144
#define TOPK 16
#define ZTOPK 8
#define EPS_TIE 1e-9f
#define RNDC 0.5f
#define NXUPD 2047           // x rows updated: 0..2046

// d_out offsets (floats): [z_response(64) | final(6208) | neurons(DD*DD) | ages(6208)]
#define OUT_FINAL 64
#define OUT_NEUR  (64 + DD)
#define OUT_AGES  (OUT_NEUR + (size_t)DD * DD)

// ws offsets (floats)
#define WS_RESP   0
#define WS_INPT   DD
#define WS_MIXX   (2 * DD)
#define WS_MIXZ   (3 * DD)
#define WS_MIXY   (4 * DD)
#define WS_SCAL   (5 * DD)           // 0 Sii,1 SmmX,2 SmiX,3 SmmZ,4 SmiZ,5 SmmY,6 SmiY,7 denomX
#define WS_SELROW (WS_SCAL + 32)     // 24 ints
#define WS_SELC   (WS_SELROW + 24)   // 24 floats: v/a
#define WS_SELW   (WS_SELC + 24)     // 24 floats: (a-1)/a
#define WS_TOTAL  (WS_SELW + 32)

// x-part tiling: 256 row-groups (8 rows) x 4 column splits of 388 chunks
#define XBLKS 1024
#define CSPL  388

__device__ __forceinline__ v4f ld4(const float* p) { return *(const v4f*)p; }
__device__ __forceinline__ v4f v4z() { v4f v; v.x = v.y = v.z = v.w = 0.f; return v; }
__device__ __forceinline__ float dot4(v4f a, v4f b) {
  return fmaf(a.x, b.x, fmaf(a.y, b.y, fmaf(a.z, b.z, a.w * b.w)));
}
__device__ __forceinline__ v4f load_inpt(const float* x, const float* yr,
                                         const float* zv, int c) {
  int col = c * 4;   // chunk boundaries never straddle 2048 / 6144 (both %4==0)
  if (col < XS) return ld4(x + col);
  if (col < Z0) return ld4(yr + (col - XS));
  return ld4(zv + (col - Z0));
}

// ---------------- Phase 1: matvec + copy rows>=2047 + mix_x + stage inpt ----
__global__ __launch_bounds__(256) void k_phase1(
    const float* __restrict__ x, const float* __restrict__ yr,
    const float* __restrict__ zv, const float* __restrict__ neurons,
    const float* __restrict__ ages, float* __restrict__ ws,
    float* __restrict__ outn)
{
  const int t = threadIdx.x;
  const int b = blockIdx.x;

  if (b < XBLKS) {
    // ---- x-part: rows rg*8..rg*8+7, columns [cs*388, cs*388+388) chunks ----
    const int rg = b >> 2, cs = b & 3;
    const int row0 = rg * 8;
    const int cbase = cs * CSPL;
    const int c0 = cbase + t;            // always valid (t<256<=388)
    const int c1 = cbase + 256 + t;      // valid iff t<132
    const bool has1 = (t < CSPL - 256);

    v4f i0 = load_inpt(x, yr, zv, c0);
    v4f i1 = has1 ? load_inpt(x, yr, zv, c1) : v4z();
    if (b < 4) {  // rg==0 blocks stage inpt (each covers its column quarter)
      ((v4f*)(ws + WS_INPT))[c0] = i0;
      if (has1) ((v4f*)(ws + WS_INPT))[c1] = i1;
    }

    float wr[8];
    #pragma unroll
    for (int r = 0; r < 8; ++r) {
      float a = ages[row0 + r];
      wr[r] = (row0 + r < NXUPD) ? (a - 1.f) / a : 0.f;
    }

    float dot[8];
    v4f m0 = v4z(), m1 = v4z();
    #pragma unroll
    for (int r = 0; r < 8; ++r) {
      const int row = row0 + r;
      const float* rp = neurons + (size_t)row * DD;
      v4f a0 = ld4(rp + 4 * c0);
      v4f a1 = has1 ? ld4(rp + 4 * c1) : v4z();
      dot[r] = dot4(a0, i0) + dot4(a1, i1);
      m0 += wr[r] * a0;
      m1 += wr[r] * a1;
      if (row >= NXUPD) {   // only row 2047 here: copy to output
        __builtin_nontemporal_store(a0, (v4f*)(outn + (size_t)row * DD + 4 * c0));
        if (has1)
          __builtin_nontemporal_store(a1, (v4f*)(outn + (size_t)row * DD + 4 * c1));
      }
    }

    // block-reduce the 8 partial dots, atomic into resp (4 col-splits/row)
    __shared__ float wred[4][8];
    const int lane = t & 63, wv = t >> 6;
    #pragma unroll
    for (int r = 0; r < 8; ++r) {
      float v = dot[r];
      #pragma unroll
      for (int m = 32; m >= 1; m >>= 1) v += __shfl_xor(v, m);
      if (lane == 0) wred[wv][r] = v;
    }
    __syncthreads();
    if (t < 8)
      atomicAdd(ws + WS_RESP + row0 + t,
                wred[0][t] + wred[1][t] + wred[2][t] + wred[3][t]);

    atomicAdd(ws + WS_MIXX + 4 * c0 + 0, m0.x);
    atomicAdd(ws + WS_MIXX + 4 * c0 + 1, m0.y);
    atomicAdd(ws + WS_MIXX + 4 * c0 + 2, m0.z);
    atomicAdd(ws + WS_MIXX + 4 * c0 + 3, m0.w);
    if (has1) {
      atomicAdd(ws + WS_MIXX + 4 * c1 + 0, m1.x);
      atomicAdd(ws + WS_MIXX + 4 * c1 + 1, m1.y);
      atomicAdd(ws + WS_MIXX + 4 * c1 + 2, m1.z);
      atomicAdd(ws + WS_MIXX + 4 * c1 + 3, m1.w);
    }
  } else {
    // ---- yz-part: one full row per block, rows 2048..6207 ----
    const int row = 2048 + (b - XBLKS);
    const float* rp = neurons + (size_t)row * DD;
    float* op = outn + (size_t)row * DD;
    float dot = 0.f;
    #pragma unroll
    for (int k = 0; k < 6; ++k) {        // chunks t+256k, max 1535 < 1552
      const int c = t + 256 * k;
      v4f a = ld4(rp + 4 * c);
      v4f iv = load_inpt(x, yr, zv, c);
      dot += dot4(a, iv);
      __builtin_nontemporal_store(a, (v4f*)(op + 4 * c));
    }
    if (t < 16) {                        // epilogue chunks 1536..1551 (z region)
      const int c = 1536 + t;
      v4f a = ld4(rp + 4 * c);
      v4f iv = ld4(zv + (4 * c - Z0));
      dot += dot4(a, iv);
      __builtin_nontemporal_store(a, (v4f*)(op + 4 * c));
    }
    __shared__ float red[4];
    const int lane = t & 63, wv = t >> 6;
    #pragma unroll
    for (int m = 32; m >= 1; m >>= 1) dot += __shfl_xor(dot, m);
    if (lane == 0) red[wv] = dot;
    __syncthreads();
    if (t == 0) ws[WS_RESP + row] = red[0] + red[1] + red[2] + red[3];
  }
}

// ---------------- Phase 2: top-ks, final, z_response, ages, scalars --------
__global__ __launch_bounds__(1024) void k_phase2(
    const float* __restrict__ ages, float* __restrict__ ws, float* __restrict__ out)
{
  const int t = threadIdx.x;
  __shared__ float sv[NN];
  __shared__ float swv[64];
  __shared__ int   swi[16];
  __shared__ float s_zval[ZTOPK + 1];
  __shared__ int   s_zidx[ZTOPK + 1];
  __shared__ float s_yval[TOPK + 1];
  __shared__ int   s_yidx[TOPK + 1];
  __shared__ float s_denx, s_ty;
  __shared__ float s_z64[ZS];

  float* resp = ws + WS_RESP;

  // ---- z top-9 (wave 0, lex-max (v,-i) => jax tie-break) ----
  if (t < ZS) s_z64[t] = resp[Z0 + t];
  __syncthreads();
  if (t < 64) {
    float v = s_z64[t];
    for (int j = 0; j <= ZTOPK; ++j) {
      float bv = v; int bi = t;
      #pragma unroll
      for (int m = 1; m < 64; m <<= 1) {
        float ov = __shfl_xor(bv, m);
        int   oi = __shfl_xor(bi, m);
        if (ov > bv || (ov == bv && oi < bi)) { bv = ov; bi = oi; }
      }
      if (t == 0) { s_zval[j] = bv; s_zidx[j] = bi; }
      if (t == bi) v = -INFINITY;
    }
  }

  // ---- x max & all-zero flag ----
  float lm = -INFINITY; int nz = 0;
  for (int i = t; i < XS; i += 1024) { float v = resp[i]; lm = fmaxf(lm, v); nz |= (v != 0.f); }
  #pragma unroll
  for (int m = 1; m < 64; m <<= 1) { lm = fmaxf(lm, __shfl_xor(lm, m)); nz |= __shfl_xor(nz, m); }
  if ((t & 63) == 0) { swv[t >> 6] = lm; swi[t >> 6] = nz; }
  __syncthreads();
  if (t == 0) {
    float m2 = -INFINITY; int n2 = 0;
    for (int q = 0; q < 16; ++q) { m2 = fmaxf(m2, swv[q]); n2 |= swi[q]; }
    float tx = n2 ? 0.f : 1.f;
    s_denx = m2 + EPS_TIE * tx * RNDC;
  }
  __syncthreads();

  // ---- y top-17 ----
  for (int i = t; i < NN; i += 1024) sv[i] = resp[XS + i];
  __syncthreads();
  for (int j = 0; j <= TOPK; ++j) {
    float bv = -INFINITY; int bi = 0x7fffffff;
    for (int i = t; i < NN; i += 1024) { float v = sv[i]; if (v > bv || (v == bv && i < bi)) { bv = v; bi = i; } }
    #pragma unroll
    for (int m = 1; m < 64; m <<= 1) {
      float ov = __shfl_xor(bv, m); int oi = __shfl_xor(bi, m);
      if (ov > bv || (ov == bv && oi < bi)) { bv = ov; bi = oi; }
    }
    if ((t & 63) == 0) { swv[t >> 6] = bv; swi[t >> 6] = bi; }
    __syncthreads();
    if (t == 0) {
      float b2 = -INFINITY; int i2 = 0x7fffffff;
      for (int q = 0; q < 16; ++q)
        if (swv[q] > b2 || (swv[q] == b2 && swi[q] < i2)) { b2 = swv[q]; i2 = swi[q]; }
      s_yval[j] = b2; s_yidx[j] = i2; sv[i2] = -INFINITY;
    }
    __syncthreads();
  }
  if (t == 0) {
    float ty = 0.f;
    for (int q = 0; q < TOPK; ++q) if (s_yval[q] == s_yval[TOPK]) ty = 1.f;
    s_ty = ty;
  }
  __syncthreads();

  // ---- final + z_response ----
  const float denx  = s_denx;
  const float zlast = s_zval[ZTOPK];
  const float zden  = s_zval[0] - zlast;
  const float ylast = s_yval[TOPK];
  const float yden  = s_yval[0] - ylast + EPS_TIE * s_ty * RNDC;
  float* fin = out + OUT_FINAL;
  for (int i = t; i < DD; i += 1024) {
    float v = 0.f;
    if (i < XS) v = resp[i] / denx;
    fin[i] = v;
  }
  __syncthreads();
  if (t < ZTOPK)                  fin[Z0 + s_zidx[t]] = (s_zval[t] - zlast) / zden;
  else if (t >= 32 && t < 32 + TOPK) { int k = t - 32; fin[XS + s_yidx[k]] = (s_yval[k] - ylast) / yden; }
  if (t >= 128 && t < 192) {
    int i = t - 128;
    float v = 0.f;
    for (int k = 0; k < ZTOPK; ++k) if (s_zidx[k] == i) v = (s_zval[k] - zlast) / zden;
    out[i] = v;
  }

  // ---- ages ----
  float* oag = out + OUT_AGES;
  for (int i = t; i < DD; i += 1024) oag[i] = ages[i] + ((i < NXUPD) ? 1.f : 0.f);
  __syncthreads();
  if (t < ZTOPK + TOPK) {
    int row = (t < ZTOPK) ? (Z0 + s_zidx[t]) : (XS + s_yidx[t - ZTOPK]);
    oag[row] = ages[row] + 1.f;
  }

  // ---- scalars: ||inpt||^2, ||mix_x||^2, mix_x . inpt ----
  float sii = 0.f, smm = 0.f, smi = 0.f;
  float* inpt = ws + WS_INPT;
  float* mixx = ws + WS_MIXX;
  for (int i = t; i < DD; i += 1024) {
    float ip = inpt[i], mx = mixx[i];
    sii = fmaf(ip, ip, sii); smm = fmaf(mx, mx, smm); smi = fmaf(mx, ip, smi);
  }
  #pragma unroll
  for (int m = 1; m < 64; m <<= 1) {
    sii += __shfl_xor(sii, m); smm += __shfl_xor(smm, m); smi += __shfl_xor(smi, m);
  }
  __syncthreads();
  if ((t & 63) == 0) { int w = t >> 6; swv[w] = sii; swv[16 + w] = smm; swv[32 + w] = smi; }
  __syncthreads();
  if (t == 0) {
    float a = 0.f, b = 0.f, c = 0.f;
    for (int q = 0; q < 16; ++q) { a += swv[q]; b += swv[16 + q]; c += swv[32 + q]; }
    float* scal = ws + WS_SCAL;
    scal[0] = a; scal[1] = b; scal[2] = c; scal[7] = denx;
  }

  // ---- selected-row tables ----
  if (t < ZTOPK) {
    int row = Z0 + s_zidx[t];
    ((int*)(ws + WS_SELROW))[t] = row;
    float a = ages[row];
    ws[WS_SELC + t] = s_zval[t] / a;
    ws[WS_SELW + t] = (a - 1.f) / a;
  } else if (t >= 32 && t < 32 + TOPK) {
    int k = t - 32;
    int row = XS + s_yidx[k];
    ((int*)(ws + WS_SELROW))[ZTOPK + k] = row;
    float a = ages[row];
    ws[WS_SELC + ZTOPK + k] = s_yval[k] / a;
    ws[WS_SELW + ZTOPK + k] = (a - 1.f) / a;
  }
}

// ---------------- Phase 3a: mix_z / mix_y accumulation ---------------------
__global__ __launch_bounds__(256) void k_phase3a(
    const float* __restrict__ neurons, float* __restrict__ ws)
{
  const int b = blockIdx.x;
  const int t = threadIdx.x;
  const int row = ((const int*)(ws + WS_SELROW))[b];
  const float w = ws[WS_SELW + b];
  float* dst = ws + ((b < ZTOPK) ? WS_MIXZ : WS_MIXY);
  const float* src = neurons + (size_t)row * DD;
  #pragma unroll
  for (int k = 0; k < 6; ++k) {
    const int c = t + 256 * k;
    v4f a = ld4(src + 4 * c);
    atomicAdd(dst + 4 * c + 0, w * a.x);
    atomicAdd(dst + 4 * c + 1, w * a.y);
    atomicAdd(dst + 4 * c + 2, w * a.z);
    atomicAdd(dst + 4 * c + 3, w * a.w);
  }
  if (t < 16) {
    const int c = 1536 + t;
    v4f a = ld4(src + 4 * c);
    atomicAdd(dst + 4 * c + 0, w * a.x);
    atomicAdd(dst + 4 * c + 1, w * a.y);
    atomicAdd(dst + 4 * c + 2, w * a.z);
    atomicAdd(dst + 4 * c + 3, w * a.w);
  }
}

// ---------------- Phase 3b: mix_z / mix_y dot scalars ----------------------
__global__ __launch_bounds__(1024) void k_phase3b(float* __restrict__ ws)
{
  const int t = threadIdx.x;
  __shared__ float red[64];
  float* inpt = ws + WS_INPT;
  float smmz = 0.f, smiz = 0.f, smmy = 0.f, smiy = 0.f;
  for (int i = t; i < DD; i += 1024) {
    float ip = inpt[i];
    float mz = ws[WS_MIXZ + i], my = ws[WS_MIXY + i];
    smmz = fmaf(mz, mz, smmz); smiz = fmaf(mz, ip, smiz);
    smmy = fmaf(my, my, smmy); smiy = fmaf(my, ip, smiy);
  }
  #pragma unroll
  for (int m = 1; m < 64; m <<= 1) {
    smmz += __shfl_xor(smmz, m); smiz += __shfl_xor(smiz, m);
    smmy += __shfl_xor(smmy, m); smiy += __shfl_xor(smiy, m);
  }
  __syncthreads();
  if ((t & 63) == 0) { int w = t >> 6; red[w] = smmz; red[16 + w] = smiz; red[32 + w] = smmy; red[48 + w] = smiy; }
  __syncthreads();
  if (t == 0) {
    float a = 0.f, b = 0.f, c = 0.f, d = 0.f;
    for (int q = 0; q < 16; ++q) { a += red[q]; b += red[16 + q]; c += red[32 + q]; d += red[48 + q]; }
    ws[WS_SCAL + 3] = a; ws[WS_SCAL + 4] = b; ws[WS_SCAL + 5] = c; ws[WS_SCAL + 6] = d;
  }
}

// ---------------- Phase 4: write the 2071 updated rows ---------------------
__global__ __launch_bounds__(256) void k_phase4(
    const float* __restrict__ ages, const float* __restrict__ ws,
    float* __restrict__ outn)
{
  const int b = blockIdx.x;
  const int t = threadIdx.x;
  const float sii = ws[WS_SCAL + 0];
  int row; float c, smm, smi; const float* mix;
  if (b < NXUPD) {
    row = b;
    float a = ages[row];
    c = (ws[WS_RESP + row] / ws[WS_SCAL + 7]) / a;   // xvals[row] / age
    mix = ws + WS_MIXX; smm = ws[WS_SCAL + 1]; smi = ws[WS_SCAL + 2];
  } else {
    int k = b - NXUPD;
    row = ((const int*)(ws + WS_SELROW))[k];
    c = ws[WS_SELC + k];
    if (k < ZTOPK) { mix = ws + WS_MIXZ; smm = ws[WS_SCAL + 3]; smi = ws[WS_SCAL + 4]; }
    else           { mix = ws + WS_MIXY; smm = ws[WS_SCAL + 5]; smi = ws[WS_SCAL + 6]; }
  }
  // ||mix + c*inpt||^2 = smm + 2c*smi + c^2*sii
  const float inv = 1.f / (sqrtf(fmaf(c, fmaf(c, sii, 2.f * smi), smm)) + 1e-12f);
  const float* inpt = ws + WS_INPT;
  float* dst = outn + (size_t)row * DD;
  #pragma unroll
  for (int k = 0; k < 6; ++k) {
    const int i = t + 256 * k;
    v4f m4 = ((const v4f*)(mix))[i];
    v4f i4 = ((const v4f*)(inpt))[i];
    v4f o = (m4 + c * i4) * inv;
    __builtin_nontemporal_store(o, (v4f*)dst + i);
  }
  if (t < 16) {
    const int i = 1536 + t;
    v4f m4 = ((const v4f*)(mix))[i];
    v4f i4 = ((const v4f*)(inpt))[i];
    v4f o = (m4 + c * i4) * inv;
    __builtin_nontemporal_store(o, (v4f*)dst + i);
  }
}

// ---------------- launcher -------------------------------------------------
extern "C" void kernel_launch(void* const* d_in, const int* in_sizes, int n_in,
                              void* d_out, int out_size, void* d_ws, size_t ws_size,
                              hipStream_t stream)
{
  (void)in_sizes; (void)n_in; (void)out_size; (void)ws_size;
  const float* x    = (const float*)d_in[0];
  const float* zin  = (const float*)d_in[1];   // setup order: x, z, y_response, neurons, ages
  const float* yr   = (const float*)d_in[2];
  const float* neur = (const float*)d_in[3];
  const float* ages = (const float*)d_in[4];
  float* out = (float*)d_out;
  float* ws  = (float*)d_ws;

  hipMemsetAsync(d_ws, 0, (size_t)WS_TOTAL * sizeof(float), stream);
  k_phase1<<<XBLKS + (DD - XS), 256, 0, stream>>>(x, yr, zin, neur, ages, ws, out + OUT_NEUR);
  k_phase2<<<1, 1024, 0, stream>>>(ages, ws, out);
  k_phase3a<<<ZTOPK + TOPK, 256, 0, stream>>>(neur, ws);
  k_phase3b<<<1, 1024, 0, stream>>>(ws);
  k_phase4<<<NXUPD + ZTOPK + TOPK, 256, 0, stream>>>(ages, ws, out + OUT_NEUR);
}